// Round 6
// baseline (256.016 us; speedup 1.0000x reference)
//
#include <hip/hip_runtime.h>
#include <hip/hip_bf16.h>

// Problem constants (from reference)
#define N_NODES 100000
#define FEAT    256
#define HID     128
#define REL     2
#define BATCH   20000
#define KNEI    10

// GEMM-H geometry: H[N_NODES][384] = features[N_NODES][256] @ Wall[256][384]
#define NCOL 384            // 24 tiles of 16 weight-cols
#define NT   24
#define KT   8              // 256 / 32
#define ASTR 260            // shorts per LDS feature row (520B -> rows 2 banks apart)

typedef short bf16x8 __attribute__((ext_vector_type(8)));
typedef float f32x4  __attribute__((ext_vector_type(4)));

__device__ __forceinline__ unsigned short f2bf(float x) {
    union { float f; unsigned u; } v; v.f = x;
    unsigned r = v.u + 0x7fffu + ((v.u >> 16) & 1u);   // RNE
    return (unsigned short)(r >> 16);
}

__device__ __forceinline__ ushort4 pack4(float a, float b, float c, float d) {
    ushort4 p; p.x = f2bf(a); p.y = f2bf(b); p.z = f2bf(c); p.w = f2bf(d);
    return p;
}

// Swizzled index for logical (k in [0,256), n = weight col in [0,384)):
// fragment (kt,nt) lane reads 16B contiguous at Bsw[((kt*NT+nt)*64 + lane)*8 + j]
// with lane = ((k>>3)&3)*16 + (n&15), j = k&7. This same layout serves as the
// MFMA A-operand (A[m=lane&15][k=(lane>>4)*8+j]) with m = weight col.
__device__ __forceinline__ size_t bsw_index(int k, int n) {
    int kt = k >> 5, j = k & 7, hi = (k >> 3) & 3;
    int lane = hi * 16 + (n & 15), nt = n >> 4;
    return ((size_t)(kt * NT + nt) * 64 + lane) * 8 + j;
}

// ---------------------------------------------------------------------------
// prep_W: build Wall[256][384] bf16 in MFMA-swizzled layout.
// blocks 0..31 : cols 128+128r: (W_stc[r] @ W_det[256+128r:...]) * (1/K)
// blocks 32..33: cols 0:128   : copy of W_det rows 0..255
// ---------------------------------------------------------------------------
__global__ __launch_bounds__(256) void prep_W(const float* __restrict__ W_stc,
                                              const float* __restrict__ W_det,
                                              unsigned short* __restrict__ Bsw) {
    const int blk = blockIdx.x;
    const int tid = threadIdx.x;
    if (blk < 32) {
        const int rel   = blk >> 4;
        const int fbase = (blk & 15) * 16;
        const int n     = tid & 127;
        const int fh    = tid >> 7;
        const float* wd = W_det + (size_t)(256 + rel * HID) * HID + n;
        const float scale = 1.0f / (float)KNEI;   // fold neighbor mean here
        #pragma unroll
        for (int fo = 0; fo < 8; ++fo) {
            const int f = fbase + fh * 8 + fo;
            const float* ws = W_stc + (size_t)(rel * FEAT + f) * HID;
            float acc = 0.f;
            #pragma unroll 8
            for (int j2 = 0; j2 < HID; ++j2) acc += ws[j2] * wd[(size_t)j2 * HID];
            Bsw[bsw_index(f, 128 + rel * 128 + n)] = f2bf(acc * scale);
        }
    } else {
        const int base = (blk - 32) * 16384;
        #pragma unroll 4
        for (int i = 0; i < 64; ++i) {
            const int idx = base + i * 256 + tid;
            const int k = idx >> 7, n = idx & 127;
            Bsw[bsw_index(k, n)] = f2bf(W_det[idx]);
        }
    }
}

// ---------------------------------------------------------------------------
// gemm_H v3 (barrier-light, operands swapped):
// Block = 512 thr / 8 waves, 64 nodes. Stage features 64x256 fp32->bf16 into
// LDS once (ONE barrier), then waves run free:
//   wave w: 4 node-tiles x 3 weight-mtiles [3w, 3w+3)  (disjoint -> block
//   reads each weight fragment exactly once: 192 KB/block, 150 MB total).
// MFMA: A = weight frag (global, swizzled), B = feature frag (LDS, k-contig),
// D[row = weight col][col = node]. Per lane the 4 acc regs are 4 CONSECUTIVE
// H columns -> 8-byte ushort4 epilogue stores.
// ---------------------------------------------------------------------------
__global__ __launch_bounds__(512, 4) void gemm_H(const float* __restrict__ features,
                                                 const unsigned short* __restrict__ Bsw,
                                                 unsigned short* __restrict__ H) {
    __shared__ unsigned short Abf[64 * ASTR];    // 33280 B

    const int row0 = blockIdx.x * 64;
    const int tid  = threadIdx.x;
    const float4* F4 = (const float4*)features;

    // Stage 64 node rows (fp32 -> bf16), coalesced; clamp tail rows.
    #pragma unroll
    for (int p = 0; p < 8; ++p) {
        const int idx = p * 512 + tid;           // < 4096
        const int r   = idx >> 6;
        const int c4  = idx & 63;
        int rg = row0 + r;
        if (rg >= N_NODES) rg = N_NODES - 1;
        float4 v = F4[(size_t)rg * 64 + c4];
        *(ushort4*)(Abf + r * ASTR + c4 * 4) = pack4(v.x, v.y, v.z, v.w);
    }
    __syncthreads();                             // the only barrier

    const int w    = tid >> 6;                   // wave 0..7
    const int lane = tid & 63;
    const int quad = lane >> 4;
    const int l16  = lane & 15;
    const int mtb  = w * 3;                      // weight-mtile base (3 per wave)

    f32x4 acc[4][3];
    #pragma unroll
    for (int nt = 0; nt < 4; ++nt)
        #pragma unroll
        for (int mt = 0; mt < 3; ++mt)
            acc[nt][mt] = (f32x4){0.f, 0.f, 0.f, 0.f};

    // Feature B-frag: lane needs feat[node = ntile*16+l16][kt*32 + quad*8 ..+8]
    const unsigned short* fbase = Abf + l16 * ASTR + quad * 8;

    #pragma unroll
    for (int kt = 0; kt < KT; ++kt) {
        bf16x8 f0 = *(const bf16x8*)(fbase + (0 * 16) * ASTR + kt * 32);
        bf16x8 f1 = *(const bf16x8*)(fbase + (1 * 16) * ASTR + kt * 32);
        bf16x8 f2 = *(const bf16x8*)(fbase + (2 * 16) * ASTR + kt * 32);
        bf16x8 f3 = *(const bf16x8*)(fbase + (3 * 16) * ASTR + kt * 32);
        const unsigned short* wk = Bsw + ((size_t)(kt * NT + mtb) * 64 + lane) * 8;
        bf16x8 w0 = *(const bf16x8*)(wk);
        bf16x8 w1 = *(const bf16x8*)(wk + 512);
        bf16x8 w2 = *(const bf16x8*)(wk + 1024);
        acc[0][0] = __builtin_amdgcn_mfma_f32_16x16x32_bf16(w0, f0, acc[0][0], 0, 0, 0);
        acc[1][0] = __builtin_amdgcn_mfma_f32_16x16x32_bf16(w0, f1, acc[1][0], 0, 0, 0);
        acc[2][0] = __builtin_amdgcn_mfma_f32_16x16x32_bf16(w0, f2, acc[2][0], 0, 0, 0);
        acc[3][0] = __builtin_amdgcn_mfma_f32_16x16x32_bf16(w0, f3, acc[3][0], 0, 0, 0);
        acc[0][1] = __builtin_amdgcn_mfma_f32_16x16x32_bf16(w1, f0, acc[0][1], 0, 0, 0);
        acc[1][1] = __builtin_amdgcn_mfma_f32_16x16x32_bf16(w1, f1, acc[1][1], 0, 0, 0);
        acc[2][1] = __builtin_amdgcn_mfma_f32_16x16x32_bf16(w1, f2, acc[2][1], 0, 0, 0);
        acc[3][1] = __builtin_amdgcn_mfma_f32_16x16x32_bf16(w1, f3, acc[3][1], 0, 0, 0);
        acc[0][2] = __builtin_amdgcn_mfma_f32_16x16x32_bf16(w2, f0, acc[0][2], 0, 0, 0);
        acc[1][2] = __builtin_amdgcn_mfma_f32_16x16x32_bf16(w2, f1, acc[1][2], 0, 0, 0);
        acc[2][2] = __builtin_amdgcn_mfma_f32_16x16x32_bf16(w2, f2, acc[2][2], 0, 0, 0);
        acc[3][2] = __builtin_amdgcn_mfma_f32_16x16x32_bf16(w2, f3, acc[3][2], 0, 0, 0);
    }

    // Epilogue: D col = l16 -> node within tile; D row = quad*4+r -> weight col.
    // Per (ntile, mt): 4 consecutive H columns -> one 8B store.
    #pragma unroll
    for (int nt = 0; nt < 4; ++nt) {
        const int node = row0 + nt * 16 + l16;
        if (node < N_NODES) {
            unsigned short* hrow = H + (size_t)node * NCOL + quad * 4;
            #pragma unroll
            for (int mt = 0; mt < 3; ++mt) {
                f32x4 a = acc[nt][mt];
                *(ushort4*)(hrow + (mtb + mt) * 16) = pack4(a[0], a[1], a[2], a[3]);
            }
        }
    }
}

// ---------------------------------------------------------------------------
// gather_out: out[b] = relu( H[self, 0:128] + sum_k H[idx0_k, 128:256]
//                                           + sum_k H[idx1_k, 256:384] )
// (mean scale folded into Wall). One wave per batch element; lane owns one
// dword (2 bf16 cols); each gather = 64 lanes x 4B = 256B coalesced chunk.
// ---------------------------------------------------------------------------
__global__ __launch_bounds__(256) void gather_out(const int* __restrict__ nodes,
                                                  const int* __restrict__ neigh_idx,
                                                  const unsigned short* __restrict__ H,
                                                  float* __restrict__ out) {
    const int w    = threadIdx.x >> 6;
    const int lane = threadIdx.x & 63;
    const int b    = blockIdx.x * 4 + w;
    if (b >= BATCH) return;

    const unsigned* Hd = (const unsigned*)H;       // row = 192 dwords
    const int self = nodes[b];
    const int* i0 = neigh_idx + (size_t)b * KNEI;
    const int* i1 = neigh_idx + (size_t)(BATCH + b) * KNEI;

    union { unsigned u; float f; } lo, hi;
    unsigned u = Hd[(size_t)self * 192 + lane];
    lo.u = u << 16;            // col 2*lane
    hi.u = u & 0xffff0000u;    // col 2*lane+1
    float a0 = lo.f, a1 = hi.f;

    #pragma unroll
    for (int k = 0; k < KNEI; ++k) {
        unsigned v = Hd[(size_t)i0[k] * 192 + 64 + lane];
        lo.u = v << 16; hi.u = v & 0xffff0000u;
        a0 += lo.f; a1 += hi.f;
    }
    #pragma unroll
    for (int k = 0; k < KNEI; ++k) {
        unsigned v = Hd[(size_t)i1[k] * 192 + 128 + lane];
        lo.u = v << 16; hi.u = v & 0xffff0000u;
        a0 += lo.f; a1 += hi.f;
    }

    float2 r;
    r.x = a0 > 0.f ? a0 : 0.f;
    r.y = a1 > 0.f ? a1 : 0.f;
    ((float2*)(out + (size_t)b * HID))[lane] = r;
}

extern "C" void kernel_launch(void* const* d_in, const int* in_sizes, int n_in,
                              void* d_out, int out_size, void* d_ws, size_t ws_size,
                              hipStream_t stream) {
    const int*   nodes     = (const int*)d_in[0];
    const int*   neigh_idx = (const int*)d_in[1];
    const float* features  = (const float*)d_in[2];
    const float* W_stc     = (const float*)d_in[3];
    const float* W_det     = (const float*)d_in[4];
    float* out = (float*)d_out;

    // ws layout: Bsw 256*384*2B = 192KB (round to 256KB) | H 100000*384*2B = 76.8MB
    unsigned short* Bsw = (unsigned short*)d_ws;
    unsigned short* H   = (unsigned short*)((char*)d_ws + 256 * 1024);

    prep_W<<<34, 256, 0, stream>>>(W_stc, W_det, Bsw);
    gemm_H<<<(N_NODES + 63) / 64, 512, 0, stream>>>(features, Bsw, H);
    gather_out<<<(BATCH + 3) / 4, 256, 0, stream>>>(nodes, neigh_idx, H, out);
}